// Round 1
// baseline (608.879 us; speedup 1.0000x reference)
//
#include <hip/hip_runtime.h>
#include <math.h>

// KNN (KNeighborsClassifier, weights='distance'): B=1024 queries, N=100000 train, D=64,
// K=16 neighbors, 10 classes. Outputs: argmax [B] then proba [B*10], all float32 in d_out.

constexpr int D      = 64;
constexpr int TQ     = 64;    // queries per block (phase A)
constexpr int TP     = 128;   // train points per LDS tile
constexpr int NCHUNK = 64;    // train chunks (phase A grid.y)
constexpr int K      = 16;    // neighbors
constexpr int NCLS   = 10;    // classes

// ---------------------------------------------------------------- Phase A ----
// grid (B/TQ, NCHUNK) x 256 threads. For each (query-tile, train-chunk) produce
// the chunk-local top-K (d2, idx), sorted ascending (idx tiebreak), into d_ws.
__global__ __launch_bounds__(256) void knn_partial(
    const float* __restrict__ x, const float* __restrict__ train,
    float* __restrict__ cand_d2, int* __restrict__ cand_idx,
    int N, int chunkLen)
{
  __shared__ float xs[TQ][D + 1];    // 64x65 floats, +1 pad vs bank conflicts
  __shared__ float x2s[TQ];
  __shared__ float ts[TP][D + 1];    // 128x65 floats; reused as d2 tile and merge lists
  __shared__ float t2s[TP];

  const int qt  = blockIdx.x;
  const int ch  = blockIdx.y;
  const int tid = threadIdx.x;
  const int q0  = qt * TQ;
  const int cstart = ch * chunkLen;
  const int cend   = min(N, cstart + chunkLen);
  const int tx = tid & 15, ty = tid >> 4;

  // stage x tile (coalesced float4)
  for (int f = tid; f < TQ * D / 4; f += 256) {
    int r = f >> 4, c = (f & 15) << 2;
    const float4 v = *reinterpret_cast<const float4*>(&x[(size_t)(q0 + r) * D + c]);
    xs[r][c] = v.x; xs[r][c + 1] = v.y; xs[r][c + 2] = v.z; xs[r][c + 3] = v.w;
  }
  __syncthreads();
  if (tid < TQ) {
    float s = 0.f;
    #pragma unroll
    for (int dd = 0; dd < D; ++dd) { float v = xs[tid][dd]; s = fmaf(v, v, s); }
    x2s[tid] = s;
  }

  // per-thread sorted top-K list (thread serves query tid>>2, points (tid&3)+4k)
  float Ld[K]; int Li[K];
  #pragma unroll
  for (int e = 0; e < K; ++e) { Ld[e] = INFINITY; Li[e] = 0x7fffffff; }

  const int ntile = (chunkLen + TP - 1) / TP;
  for (int t = 0; t < ntile; ++t) {
    const int pstart = cstart + t * TP;
    __syncthreads();  // previous iteration's d2/scan reads of ts are done
    // stage train tile (coalesced float4); OOB rows -> zeros
    for (int f = tid; f < TP * D / 4; f += 256) {
      int r = f >> 4, c = (f & 15) << 2;
      int p = pstart + r;
      float4 v = make_float4(0.f, 0.f, 0.f, 0.f);
      if (p < cend) v = *reinterpret_cast<const float4*>(&train[(size_t)p * D + c]);
      ts[r][c] = v.x; ts[r][c + 1] = v.y; ts[r][c + 2] = v.z; ts[r][c + 3] = v.w;
    }
    __syncthreads();
    if (tid < TP) {
      float s = 0.f;
      #pragma unroll
      for (int dd = 0; dd < D; ++dd) { float v = ts[tid][dd]; s = fmaf(v, v, s); }
      t2s[tid] = (pstart + tid < cend) ? s : INFINITY;  // OOB -> d2 = INF
    }
    __syncthreads();

    // 4x8 register micro-tile of dot products over 16x16 thread grid
    float acc[4][8];
    #pragma unroll
    for (int i = 0; i < 4; ++i)
      #pragma unroll
      for (int j = 0; j < 8; ++j) acc[i][j] = 0.f;

    for (int dd = 0; dd < D; ++dd) {
      float a[4], b[8];
      #pragma unroll
      for (int i = 0; i < 4; ++i) a[i] = xs[ty * 4 + i][dd];
      #pragma unroll
      for (int j = 0; j < 8; ++j) b[j] = ts[tx * 8 + j][dd];
      #pragma unroll
      for (int i = 0; i < 4; ++i)
        #pragma unroll
        for (int j = 0; j < 8; ++j) acc[i][j] = fmaf(a[i], b[j], acc[i][j]);
    }
    __syncthreads();  // all ts reads done; reuse ts as d2 tile

    float* d2s = &ts[0][0];  // viewed as [TQ][TP+1], 64*129=8256 <= 8320 floats
    #pragma unroll
    for (int i = 0; i < 4; ++i) {
      int q = ty * 4 + i;
      float xq = x2s[q];
      #pragma unroll
      for (int j = 0; j < 8; ++j) {
        int p = tx * 8 + j;
        float d2 = fmaxf(xq - 2.f * acc[i][j] + t2s[p], 0.f);  // OOB stays INF
        d2s[q * (TP + 1) + p] = d2;
      }
    }
    __syncthreads();

    // selection scan: 4 threads per query, interleaved points, ascending idx
    {
      const int q = tid >> 2, l4 = tid & 3;
      for (int pp = l4; pp < TP; pp += 4) {
        float dv = d2s[q * (TP + 1) + pp];
        if (dv < Ld[K - 1]) {
          Ld[K - 1] = dv; Li[K - 1] = pstart + pp;
          #pragma unroll
          for (int e = K - 1; e > 0; --e) {
            if (Ld[e] < Ld[e - 1]) {  // strict <: earlier (smaller) idx stays first on ties
              float td = Ld[e]; Ld[e] = Ld[e - 1]; Ld[e - 1] = td;
              int   ti = Li[e]; Li[e] = Li[e - 1]; Li[e - 1] = ti;
            }
          }
        }
      }
    }
  }

  __syncthreads();
  // merge the 4 per-thread lists of each query; reuse ts as scratch
  float* md = &ts[0][0];                         // 4096 floats
  int*   mi = reinterpret_cast<int*>(md + TQ * 4 * K);  // 4096 ints, total 8192 <= 8320
  {
    const int q = tid >> 2, l4 = tid & 3;
    #pragma unroll
    for (int e = 0; e < K; ++e) {
      md[(q * 4 + l4) * K + e] = Ld[e];
      mi[(q * 4 + l4) * K + e] = Li[e];
    }
  }
  __syncthreads();
  if (tid < TQ) {
    const int q = tid;
    float* od = &cand_d2[(((size_t)(q0 + q)) * NCHUNK + ch) * K];
    int*   oi = &cand_idx[(((size_t)(q0 + q)) * NCHUNK + ch) * K];
    int h0 = 0, h1 = 0, h2 = 0, h3 = 0;
    for (int r = 0; r < K; ++r) {
      float bd = INFINITY; int bi = 0x7fffffff; int bt = 0;
      {
        float dv = (h0 < K) ? md[(q * 4 + 0) * K + h0] : INFINITY;
        int   iv = (h0 < K) ? mi[(q * 4 + 0) * K + h0] : 0x7fffffff;
        if (dv < bd || (dv == bd && iv < bi)) { bd = dv; bi = iv; bt = 0; }
      }
      {
        float dv = (h1 < K) ? md[(q * 4 + 1) * K + h1] : INFINITY;
        int   iv = (h1 < K) ? mi[(q * 4 + 1) * K + h1] : 0x7fffffff;
        if (dv < bd || (dv == bd && iv < bi)) { bd = dv; bi = iv; bt = 1; }
      }
      {
        float dv = (h2 < K) ? md[(q * 4 + 2) * K + h2] : INFINITY;
        int   iv = (h2 < K) ? mi[(q * 4 + 2) * K + h2] : 0x7fffffff;
        if (dv < bd || (dv == bd && iv < bi)) { bd = dv; bi = iv; bt = 2; }
      }
      {
        float dv = (h3 < K) ? md[(q * 4 + 3) * K + h3] : INFINITY;
        int   iv = (h3 < K) ? mi[(q * 4 + 3) * K + h3] : 0x7fffffff;
        if (dv < bd || (dv == bd && iv < bi)) { bd = dv; bi = iv; bt = 3; }
      }
      if (bt == 0) h0++; else if (bt == 1) h1++; else if (bt == 2) h2++; else h3++;
      od[r] = bd; oi[r] = bi;
    }
  }
}

// ---------------------------------------------------------------- Phase B ----
// one block (1 wave) per query: merge NCHUNK sorted K-lists via 16 rounds of
// wave-argmin, accumulate inverse-distance votes, normalize, argmax.
__global__ __launch_bounds__(64) void knn_finalize(
    const float* __restrict__ cand_d2, const int* __restrict__ cand_idx,
    const int* __restrict__ labels, float* __restrict__ out, int B)
{
  const int q = blockIdx.x;
  const int lane = threadIdx.x;   // lane == chunk

  float Ld[K]; int Li[K];
  const float* pd = &cand_d2[((size_t)q * NCHUNK + lane) * K];
  const int*   pi = &cand_idx[((size_t)q * NCHUNK + lane) * K];
  #pragma unroll
  for (int e = 0; e < K; ++e) { Ld[e] = pd[e]; Li[e] = pi[e]; }

  float accw[NCLS]; float acci[NCLS];
  #pragma unroll
  for (int c = 0; c < NCLS; ++c) { accw[c] = 0.f; acci[c] = 0.f; }
  int anyInf = 0;

  for (int r = 0; r < K; ++r) {
    float bd = Ld[0]; int bi = Li[0];
    #pragma unroll
    for (int s = 0; s < 6; ++s) {
      int off = 32 >> s;
      float od = __shfl_xor(bd, off);
      int   oi = __shfl_xor(bi, off);
      if (od < bd || (od == bd && oi < bi)) { bd = od; bi = oi; }
    }
    // consume from winning lane's list (static shift-down, no dynamic indexing)
    if (Ld[0] == bd && Li[0] == bi) {
      #pragma unroll
      for (int e = 0; e < K - 1; ++e) { Ld[e] = Ld[e + 1]; Li[e] = Li[e + 1]; }
      Ld[K - 1] = INFINITY; Li[K - 1] = 0x7fffffff;
    }
    float dist = sqrtf(fmaxf(bd, 0.f));
    int lab = labels[bi];
    int isz = (dist == 0.f) ? 1 : 0;
    anyInf |= isz;
    float w = 1.f / dist;  // inf when dist==0; accw discarded in that case
    #pragma unroll
    for (int c = 0; c < NCLS; ++c) {
      accw[c] += (lab == c) ? w : 0.f;
      acci[c] += (lab == c && isz) ? 1.f : 0.f;
    }
  }

  if (lane == 0) {
    float proba[NCLS]; float s = 0.f;
    #pragma unroll
    for (int c = 0; c < NCLS; ++c) { proba[c] = anyInf ? acci[c] : accw[c]; s += proba[c]; }
    if (s == 0.f) s = 1.f;
    #pragma unroll
    for (int c = 0; c < NCLS; ++c) proba[c] = proba[c] / s;
    int best = 0; float bv = proba[0];
    #pragma unroll
    for (int c = 1; c < NCLS; ++c) if (proba[c] > bv) { bv = proba[c]; best = c; }  // first max, like np.argmax
    out[q] = (float)best;
    #pragma unroll
    for (int c = 0; c < NCLS; ++c) out[B + q * NCLS + c] = proba[c];
  }
}

extern "C" void kernel_launch(void* const* d_in, const int* in_sizes, int n_in,
                              void* d_out, int out_size, void* d_ws, size_t ws_size,
                              hipStream_t stream)
{
  const float* x     = (const float*)d_in[0];
  const float* train = (const float*)d_in[1];
  const int*   labels = (const int*)d_in[2];
  float* out = (float*)d_out;

  const int B = in_sizes[0] / D;   // 1024
  const int N = in_sizes[2];       // 100000
  const int chunkLen = (N + NCHUNK - 1) / NCHUNK;

  float* cand_d2 = (float*)d_ws;                                   // B*NCHUNK*K floats (4 MB)
  int*   cand_idx = (int*)(cand_d2 + (size_t)B * NCHUNK * K);      // B*NCHUNK*K ints (4 MB)

  dim3 gridA(B / TQ, NCHUNK);
  knn_partial<<<gridA, 256, 0, stream>>>(x, train, cand_d2, cand_idx, N, chunkLen);
  knn_finalize<<<B, 64, 0, stream>>>(cand_d2, cand_idx, labels, out, B);
}

// Round 3
// 322.839 us; speedup vs baseline: 1.8860x; 1.8860x over previous
//
#include <hip/hip_runtime.h>
#include <math.h>

// KNN (weights='distance'): B=1024 queries, N=100000 train, D=64, K=16, 10 classes.
// Outputs: argmax [B] then proba [B*10], float32, concatenated in d_out.
// Phase A: bf16x3-split MFMA distances (hi*hi + hi*lo + lo*hi), top-16 per (query,chunk).
// Phase B: merge chunks -> top-24 approx, exact fp32 rescore, top-16, weighted vote.

constexpr int D      = 64;
constexpr int TQ     = 64;    // queries per block
constexpr int TP     = 64;    // train points per tile
constexpr int NCHUNK = 48;    // train chunks (grid.y); 16*48 = 768 blocks = 3/CU
constexpr int K      = 16;    // neighbors
constexpr int M      = 24;    // rescored candidates (top-M approx -> exact top-K)
constexpr int NCLS   = 10;    // classes
constexpr int TSP    = 72;    // LDS pitch in bf16 elems (144B, 16B-aligned rows)

typedef __attribute__((ext_vector_type(8))) short bf16x8_t;
typedef __attribute__((ext_vector_type(4))) float f32x4_t;

__device__ __forceinline__ unsigned short f32_to_bf16_rne(float f) {
  unsigned int u = __float_as_uint(f);
  unsigned int r = u + 0x7FFFu + ((u >> 16) & 1u);
  return (unsigned short)(r >> 16);
}

// ---------------------------------------------------------------- Phase A ----
__global__ __launch_bounds__(256) void knn_partial(
    const float* __restrict__ x, const float* __restrict__ train,
    float* __restrict__ cand_d2, int* __restrict__ cand_idx,
    int N, int chunkLen)
{
  // smem carve (floats): ts_hi+ts_lo [2*64*72 bf16 = 4608 f] | d2s [64*65 = 4160 f] | t2s 64 | x2s 64
  __shared__ __align__(16) float smem[8896];
  unsigned short* ts_hi = reinterpret_cast<unsigned short*>(smem);          // [64][72]
  unsigned short* ts_lo = ts_hi + TQ * TSP;                                  // [64][72]
  float* d2s = smem + 4608;                                                  // [64][65]
  float* t2s = smem + 8768;
  float* x2s = smem + 8832;

  const int tid  = threadIdx.x;
  const int wave = tid >> 6, lane = tid & 63;
  const int lhalf = lane & 15, lgrp = lane >> 4;
  const int qt = blockIdx.x, ch = blockIdx.y;
  const int q0 = qt * TQ;
  const int cstart = ch * chunkLen;
  const int cend   = min(N, cstart + chunkLen);

  const int sp  = tid >> 2;   // staging: point/query row 0..63
  const int sqt = tid & 3;    // staging: quarter of the 64-dim row

  // ---- stage x tile (hi/lo bf16 + fp32 norms) ----
  {
    const float* src = &x[(size_t)(q0 + sp) * D + sqt * 16];
    float nrm = 0.f;
    #pragma unroll
    for (int i = 0; i < 4; ++i) {
      float4 v = *reinterpret_cast<const float4*>(src + i * 4);
      nrm = fmaf(v.x, v.x, nrm); nrm = fmaf(v.y, v.y, nrm);
      nrm = fmaf(v.z, v.z, nrm); nrm = fmaf(v.w, v.w, nrm);
      unsigned short h0 = f32_to_bf16_rne(v.x), h1 = f32_to_bf16_rne(v.y);
      unsigned short h2 = f32_to_bf16_rne(v.z), h3 = f32_to_bf16_rne(v.w);
      float l0f = v.x - __uint_as_float((unsigned)h0 << 16);
      float l1f = v.y - __uint_as_float((unsigned)h1 << 16);
      float l2f = v.z - __uint_as_float((unsigned)h2 << 16);
      float l3f = v.w - __uint_as_float((unsigned)h3 << 16);
      uint2 hh = make_uint2((unsigned)h0 | ((unsigned)h1 << 16), (unsigned)h2 | ((unsigned)h3 << 16));
      uint2 ll = make_uint2((unsigned)f32_to_bf16_rne(l0f) | ((unsigned)f32_to_bf16_rne(l1f) << 16),
                            (unsigned)f32_to_bf16_rne(l2f) | ((unsigned)f32_to_bf16_rne(l3f) << 16));
      *reinterpret_cast<uint2*>(&ts_hi[sp * TSP + sqt * 16 + i * 4]) = hh;
      *reinterpret_cast<uint2*>(&ts_lo[sp * TSP + sqt * 16 + i * 4]) = ll;
    }
    nrm += __shfl_xor(nrm, 1);
    nrm += __shfl_xor(nrm, 2);
    if (sqt == 0) x2s[sp] = nrm;
  }
  __syncthreads();

  // ---- hoist A fragments (wave's 16 queries) into registers ----
  const unsigned short* arow_h = &ts_hi[(wave * 16 + lhalf) * TSP + lgrp * 8];
  const unsigned short* arow_l = &ts_lo[(wave * 16 + lhalf) * TSP + lgrp * 8];
  bf16x8_t Ahi0 = *reinterpret_cast<const bf16x8_t*>(arow_h);
  bf16x8_t Ahi1 = *reinterpret_cast<const bf16x8_t*>(arow_h + 32);
  bf16x8_t Alo0 = *reinterpret_cast<const bf16x8_t*>(arow_l);
  bf16x8_t Alo1 = *reinterpret_cast<const bf16x8_t*>(arow_l + 32);
  float x2r[4];
  #pragma unroll
  for (int r = 0; r < 4; ++r) x2r[r] = x2s[wave * 16 + lgrp * 4 + r];  // C-row = wave slice + (lane>>4)*4 + r

  // per-thread sorted top-K list (thread scans query tid>>2, points (tid&3)*16+k)
  float Ld[K]; int Li[K];
  #pragma unroll
  for (int e = 0; e < K; ++e) { Ld[e] = INFINITY; Li[e] = 0x7fffffff; }

  const int ntile = (chunkLen + TP - 1) / TP;
  for (int t = 0; t < ntile; ++t) {
    const int pstart = cstart + t * TP;
    __syncthreads();  // prior frag reads of ts + scan reads of d2s done

    // ---- stage train tile (hi/lo bf16 + fp32 norms; OOB -> zeros/INF) ----
    {
      const int gp = pstart + sp;
      const bool ok = gp < cend;
      const float* src = &train[(size_t)(ok ? gp : 0) * D + sqt * 16];
      float nrm = 0.f;
      #pragma unroll
      for (int i = 0; i < 4; ++i) {
        float4 v = make_float4(0.f, 0.f, 0.f, 0.f);
        if (ok) v = *reinterpret_cast<const float4*>(src + i * 4);
        nrm = fmaf(v.x, v.x, nrm); nrm = fmaf(v.y, v.y, nrm);
        nrm = fmaf(v.z, v.z, nrm); nrm = fmaf(v.w, v.w, nrm);
        unsigned short h0 = f32_to_bf16_rne(v.x), h1 = f32_to_bf16_rne(v.y);
        unsigned short h2 = f32_to_bf16_rne(v.z), h3 = f32_to_bf16_rne(v.w);
        float l0f = v.x - __uint_as_float((unsigned)h0 << 16);
        float l1f = v.y - __uint_as_float((unsigned)h1 << 16);
        float l2f = v.z - __uint_as_float((unsigned)h2 << 16);
        float l3f = v.w - __uint_as_float((unsigned)h3 << 16);
        uint2 hh = make_uint2((unsigned)h0 | ((unsigned)h1 << 16), (unsigned)h2 | ((unsigned)h3 << 16));
        uint2 ll = make_uint2((unsigned)f32_to_bf16_rne(l0f) | ((unsigned)f32_to_bf16_rne(l1f) << 16),
                              (unsigned)f32_to_bf16_rne(l2f) | ((unsigned)f32_to_bf16_rne(l3f) << 16));
        *reinterpret_cast<uint2*>(&ts_hi[sp * TSP + sqt * 16 + i * 4]) = hh;
        *reinterpret_cast<uint2*>(&ts_lo[sp * TSP + sqt * 16 + i * 4]) = ll;
      }
      nrm += __shfl_xor(nrm, 1);
      nrm += __shfl_xor(nrm, 2);
      if (sqt == 0) t2s[sp] = ok ? nrm : INFINITY;
    }
    __syncthreads();

    // ---- MFMA: wave handles queries [16*wave,16*wave+16) x all 64 points ----
    #pragma unroll
    for (int ct = 0; ct < 4; ++ct) {
      const unsigned short* brow_h = &ts_hi[(ct * 16 + lhalf) * TSP + lgrp * 8];
      const unsigned short* brow_l = &ts_lo[(ct * 16 + lhalf) * TSP + lgrp * 8];
      bf16x8_t Bhi0 = *reinterpret_cast<const bf16x8_t*>(brow_h);
      bf16x8_t Bhi1 = *reinterpret_cast<const bf16x8_t*>(brow_h + 32);
      bf16x8_t Blo0 = *reinterpret_cast<const bf16x8_t*>(brow_l);
      bf16x8_t Blo1 = *reinterpret_cast<const bf16x8_t*>(brow_l + 32);
      f32x4_t c = {0.f, 0.f, 0.f, 0.f};
      c = __builtin_amdgcn_mfma_f32_16x16x32_bf16(Ahi0, Bhi0, c, 0, 0, 0);
      c = __builtin_amdgcn_mfma_f32_16x16x32_bf16(Ahi1, Bhi1, c, 0, 0, 0);
      c = __builtin_amdgcn_mfma_f32_16x16x32_bf16(Ahi0, Blo0, c, 0, 0, 0);
      c = __builtin_amdgcn_mfma_f32_16x16x32_bf16(Ahi1, Blo1, c, 0, 0, 0);
      c = __builtin_amdgcn_mfma_f32_16x16x32_bf16(Alo0, Bhi0, c, 0, 0, 0);
      c = __builtin_amdgcn_mfma_f32_16x16x32_bf16(Alo1, Bhi1, c, 0, 0, 0);
      const float t2p = t2s[ct * 16 + lhalf];
      #pragma unroll
      for (int r = 0; r < 4; ++r) {
        float d2v = fmaxf(fmaf(-2.f, c[r], x2r[r]) + t2p, 0.f);  // OOB: t2p=INF -> INF
        d2s[(wave * 16 + lgrp * 4 + r) * 65 + ct * 16 + lhalf] = d2v;  // FIX: +wave*16
      }
    }
    __syncthreads();

    // ---- selection scan: 4 threads/query, contiguous sixteenths ----
    {
      const int q = tid >> 2, l4 = tid & 3;
      #pragma unroll
      for (int k = 0; k < 16; ++k) {
        const int pp = l4 * 16 + k;
        float dv = d2s[q * 65 + pp];
        if (dv < Ld[K - 1]) {
          Ld[K - 1] = dv; Li[K - 1] = pstart + pp;
          #pragma unroll
          for (int e = K - 1; e > 0; --e) {
            if (Ld[e] < Ld[e - 1]) {  // strict <: ascending-idx scan keeps ties stable
              float td = Ld[e]; Ld[e] = Ld[e - 1]; Ld[e - 1] = td;
              int   ti = Li[e]; Li[e] = Li[e - 1]; Li[e - 1] = ti;
            }
          }
        }
      }
    }
  }

  __syncthreads();
  // ---- merge the 4 per-thread lists per query; ts + d2s areas are dead ----
  float* md = d2s;                           // 4096 floats
  int*   mi = reinterpret_cast<int*>(smem);  // 4096 ints (ts area)
  #pragma unroll
  for (int e = 0; e < K; ++e) { md[tid * K + e] = Ld[e]; mi[tid * K + e] = Li[e]; }
  __syncthreads();
  if (tid < TQ) {
    const int q = tid;
    float* od = &cand_d2[(((size_t)(q0 + q)) * NCHUNK + ch) * K];
    int*   oi = &cand_idx[(((size_t)(q0 + q)) * NCHUNK + ch) * K];
    int h0 = 0, h1 = 0, h2 = 0, h3 = 0;
    for (int r = 0; r < K; ++r) {
      float bd = INFINITY; int bi = 0x7fffffff; int bt = 0;
      {
        float dv = (h0 < K) ? md[(q * 4 + 0) * K + h0] : INFINITY;
        int   iv = (h0 < K) ? mi[(q * 4 + 0) * K + h0] : 0x7fffffff;
        if (dv < bd || (dv == bd && iv < bi)) { bd = dv; bi = iv; bt = 0; }
      }
      {
        float dv = (h1 < K) ? md[(q * 4 + 1) * K + h1] : INFINITY;
        int   iv = (h1 < K) ? mi[(q * 4 + 1) * K + h1] : 0x7fffffff;
        if (dv < bd || (dv == bd && iv < bi)) { bd = dv; bi = iv; bt = 1; }
      }
      {
        float dv = (h2 < K) ? md[(q * 4 + 2) * K + h2] : INFINITY;
        int   iv = (h2 < K) ? mi[(q * 4 + 2) * K + h2] : 0x7fffffff;
        if (dv < bd || (dv == bd && iv < bi)) { bd = dv; bi = iv; bt = 2; }
      }
      {
        float dv = (h3 < K) ? md[(q * 4 + 3) * K + h3] : INFINITY;
        int   iv = (h3 < K) ? mi[(q * 4 + 3) * K + h3] : 0x7fffffff;
        if (dv < bd || (dv == bd && iv < bi)) { bd = dv; bi = iv; bt = 3; }
      }
      if (bt == 0) h0++; else if (bt == 1) h1++; else if (bt == 2) h2++; else h3++;
      od[r] = bd; oi[r] = bi;
    }
  }
}

// ---------------------------------------------------------------- Phase B ----
// one block (1 wave) per query: merge 48 sorted K-lists -> top-M approx,
// exact fp32 rescore of those M, exact top-K extraction, weighted vote.
__global__ __launch_bounds__(64) void knn_finalize(
    const float* __restrict__ cand_d2, const int* __restrict__ cand_idx,
    const float* __restrict__ x, const float* __restrict__ train,
    const int* __restrict__ labels, float* __restrict__ out, int B)
{
  const int q = blockIdx.x;
  const int lane = threadIdx.x;   // lane == chunk (lanes >= NCHUNK idle with INF)

  float Ld[K]; int Li[K];
  #pragma unroll
  for (int e = 0; e < K; ++e) { Ld[e] = INFINITY; Li[e] = 0x7fffffff; }
  if (lane < NCHUNK) {
    const float* pd = &cand_d2[((size_t)q * NCHUNK + lane) * K];
    const int*   pi = &cand_idx[((size_t)q * NCHUNK + lane) * K];
    #pragma unroll
    for (int e = 0; e < K; ++e) { Ld[e] = pd[e]; Li[e] = pi[e]; }
  }

  // ---- extract top-M by approx d2; lane r keeps the round-r winner ----
  int myCand = 0;
  for (int r = 0; r < M; ++r) {
    float bd = Ld[0]; int bi = Li[0];
    #pragma unroll
    for (int s = 0; s < 6; ++s) {
      int off = 32 >> s;
      float od = __shfl_xor(bd, off);
      int   oi = __shfl_xor(bi, off);
      if (od < bd || (od == bd && oi < bi)) { bd = od; bi = oi; }
    }
    if (Ld[0] == bd && Li[0] == bi) {  // pop winner (indices unique -> one lane)
      #pragma unroll
      for (int e = 0; e < K - 1; ++e) { Ld[e] = Ld[e + 1]; Li[e] = Li[e + 1]; }
      Ld[K - 1] = INFINITY; Li[K - 1] = 0x7fffffff;
    }
    if (lane == r) myCand = bi;
  }

  // ---- exact fp32 rescore (lane i owns candidate i) ----
  float curD = INFINITY; int curI = 0x7fffffff;
  if (lane < M) {
    curI = myCand;
    const float* xr = &x[(size_t)q * D];
    const float* tr = &train[(size_t)curI * D];
    float dot = 0.f, x2 = 0.f, t2 = 0.f;
    #pragma unroll
    for (int i = 0; i < D / 4; ++i) {
      float4 xv = *reinterpret_cast<const float4*>(xr + i * 4);
      float4 tv = *reinterpret_cast<const float4*>(tr + i * 4);
      dot = fmaf(xv.x, tv.x, dot); dot = fmaf(xv.y, tv.y, dot);
      dot = fmaf(xv.z, tv.z, dot); dot = fmaf(xv.w, tv.w, dot);
      x2  = fmaf(xv.x, xv.x, x2);  x2  = fmaf(xv.y, xv.y, x2);
      x2  = fmaf(xv.z, xv.z, x2);  x2  = fmaf(xv.w, xv.w, x2);
      t2  = fmaf(tv.x, tv.x, t2);  t2  = fmaf(tv.y, tv.y, t2);
      t2  = fmaf(tv.z, tv.z, t2);  t2  = fmaf(tv.w, tv.w, t2);
    }
    curD = fmaxf(x2 - 2.f * dot + t2, 0.f);
  }

  // ---- final top-K by exact d2 + weighted votes ----
  float accw[NCLS]; float acci[NCLS];
  #pragma unroll
  for (int c = 0; c < NCLS; ++c) { accw[c] = 0.f; acci[c] = 0.f; }
  int anyInf = 0;

  for (int r = 0; r < K; ++r) {
    float bd = curD; int bi = curI;
    #pragma unroll
    for (int s = 0; s < 6; ++s) {
      int off = 32 >> s;
      float od = __shfl_xor(bd, off);
      int   oi = __shfl_xor(bi, off);
      if (od < bd || (od == bd && oi < bi)) { bd = od; bi = oi; }
    }
    if (curD == bd && curI == bi) { curD = INFINITY; curI = 0x7fffffff; }  // pop
    float dist = sqrtf(bd);
    int lab = labels[bi];
    int isz = (dist == 0.f) ? 1 : 0;
    anyInf |= isz;
    float w = 1.f / dist;
    #pragma unroll
    for (int c = 0; c < NCLS; ++c) {
      accw[c] += (lab == c) ? w : 0.f;
      acci[c] += (lab == c && isz) ? 1.f : 0.f;
    }
  }

  if (lane == 0) {
    float proba[NCLS]; float s = 0.f;
    #pragma unroll
    for (int c = 0; c < NCLS; ++c) { proba[c] = anyInf ? acci[c] : accw[c]; s += proba[c]; }
    if (s == 0.f) s = 1.f;
    #pragma unroll
    for (int c = 0; c < NCLS; ++c) proba[c] = proba[c] / s;
    int best = 0; float bv = proba[0];
    #pragma unroll
    for (int c = 1; c < NCLS; ++c) if (proba[c] > bv) { bv = proba[c]; best = c; }  // first max, like np.argmax
    out[q] = (float)best;
    #pragma unroll
    for (int c = 0; c < NCLS; ++c) out[B + q * NCLS + c] = proba[c];
  }
}

extern "C" void kernel_launch(void* const* d_in, const int* in_sizes, int n_in,
                              void* d_out, int out_size, void* d_ws, size_t ws_size,
                              hipStream_t stream)
{
  const float* x      = (const float*)d_in[0];
  const float* train  = (const float*)d_in[1];
  const int*   labels = (const int*)d_in[2];
  float* out = (float*)d_out;

  const int B = in_sizes[0] / D;   // 1024
  const int N = in_sizes[2];       // 100000
  const int chunkLen = (N + NCHUNK - 1) / NCHUNK;

  float* cand_d2 = (float*)d_ws;                                 // B*NCHUNK*K floats (3 MB)
  int*   cand_idx = (int*)(cand_d2 + (size_t)B * NCHUNK * K);    // B*NCHUNK*K ints (3 MB)

  dim3 gridA(B / TQ, NCHUNK);
  knn_partial<<<gridA, 256, 0, stream>>>(x, train, cand_d2, cand_idx, N, chunkLen);
  knn_finalize<<<B, 64, 0, stream>>>(cand_d2, cand_idx, x, train, labels, out, B);
}